// Round 15
// baseline (108.195 us; speedup 1.0000x reference)
//
#include <hip/hip_runtime.h>
#include <hip/hip_bf16.h>
#include <math.h>

// VectorQuantizer: z [65536 x 64] fp32, codebook [1024 x 64] fp32.
// dist = (||z||^2 - 2 z.e) + ||e||^2, argmin_k, first-occurrence ties.
// Numerics: exact np pairwise sumsq for S/cn; d via f16 split-2 3-pass
// MFMA (err ~1e-8 << absorption bin 7.6e-6); comparison in the 2^9 basis
// (R18/R21-passed): dist9 = (S*2^9 - ds) + cn*2^9; (val, lowest-k).
// Per-element arithmetic bit-identical to R21 (passed, absmax 0).
//
// R23 post-mortem: no-drain counted-vmcnt LDS dbuf = NULL (44us, 11th
// structural null at 44+-1.5). MfmaUtil 22% x 105k cy == 1536 MFMA/SIMD
// x 16.1 cy exactly -> clock IS 2.4GHz (DVFS theory dead). The one axis
// never varied: ROWS PER WAVE. Every variant uses 32 rows/wave, so each
// SIMD redundantly reads the 256KB B-stream twice (512 x 1KB-instrs,
// 2MB/CU through L1-or-LDS) -- the only per-SIMD quantity that scales
// with wave count rather than work. R24: 64 rows/wave (4 rt), 256
// rows/block, grid=256 = exactly 1 block/CU, 1 wave/SIMD. B-reads/SIMD
// HALVE; MFMA+EPI per SIMD unchanged. z-tile via dynamic LDS (68KB,
// fits 160KB at 1 block/CU). VGPR ~210 under launch_bounds(256,1).

#define D      64
#define K      1024
#define BLOCK  256
#define ROWS   256

typedef _Float16 half8_t __attribute__((ext_vector_type(8)));
typedef float    floatx4 __attribute__((ext_vector_type(4)));

// ws layout
#define WS_CN_OFF    0            // float[1024]         (4 KB)
#define WS_EF_OFF    4096         // _Float16[131072]    (256 KB)
// group-contiguous layout: group g (16 codes) occupies bytes
// [g*4096, (g+1)*4096): slot s=(spl*2+ch) at g*4096 + s*1024 + 16*lane,
// lane = quad*16 + l16 (MFMA B lane order).

// numpy pairwise sumsq (n=64): 8 stride-8 accs of fl(x^2), tree combine.
__device__ __forceinline__ float np_sumsq64_p(const float* __restrict__ x) {
    float r[8];
    {
        float4 v0 = *(const float4*)(x);
        float4 v1 = *(const float4*)(x + 4);
        r[0] = __fmul_rn(v0.x, v0.x); r[1] = __fmul_rn(v0.y, v0.y);
        r[2] = __fmul_rn(v0.z, v0.z); r[3] = __fmul_rn(v0.w, v0.w);
        r[4] = __fmul_rn(v1.x, v1.x); r[5] = __fmul_rn(v1.y, v1.y);
        r[6] = __fmul_rn(v1.z, v1.z); r[7] = __fmul_rn(v1.w, v1.w);
    }
#pragma unroll
    for (int i = 8; i < 64; i += 8) {
        float4 v0 = *(const float4*)(x + i);
        float4 v1 = *(const float4*)(x + i + 4);
        r[0] = __fadd_rn(r[0], __fmul_rn(v0.x, v0.x));
        r[1] = __fadd_rn(r[1], __fmul_rn(v0.y, v0.y));
        r[2] = __fadd_rn(r[2], __fmul_rn(v0.z, v0.z));
        r[3] = __fadd_rn(r[3], __fmul_rn(v0.w, v0.w));
        r[4] = __fadd_rn(r[4], __fmul_rn(v1.x, v1.x));
        r[5] = __fadd_rn(r[5], __fmul_rn(v1.y, v1.y));
        r[6] = __fadd_rn(r[6], __fmul_rn(v1.z, v1.z));
        r[7] = __fadd_rn(r[7], __fmul_rn(v1.w, v1.w));
    }
    return __fadd_rn(__fadd_rn(__fadd_rn(r[0], r[1]), __fadd_rn(r[2], r[3])),
                     __fadd_rn(__fadd_rn(r[4], r[5]), __fadd_rn(r[6], r[7])));
}

// ---- precompute: code norms + f16 split-2 B-frags, group-contiguous ----
__global__ void vq_pre(const float* __restrict__ cb, float* __restrict__ cn,
                       _Float16* __restrict__ ef) {
    const int k = blockIdx.x * 64 + threadIdx.x;
    if (k >= K) return;
    cn[k] = np_sumsq64_p(cb + (long)k * D);
    const int t = k >> 6, ct = (k >> 4) & 3, l16 = k & 15;
#pragma unroll
    for (int ch = 0; ch < 2; ++ch)
#pragma unroll
        for (int quad = 0; quad < 4; ++quad) {
            const float* p = cb + (long)k * D + ch * 32 + quad * 8;
            half8_t h1, h2;
#pragma unroll
            for (int j = 0; j < 8; ++j) {
                float x10 = __fmul_rn(p[j], 1024.0f);        // exact pow2 scale
                _Float16 g1 = (_Float16)x10;
                h1[j] = g1;
                h2[j] = (_Float16)(__fmul_rn(__fsub_rn(x10, (float)g1), 2048.0f));
            }
            // group g = t*4+ct; half-offset: g*2048 + slot*512 + 128*quad + 8*l16
            const int base = (t * 4 + ct) * 2048 + 128 * quad + 8 * l16;
            *(half8_t*)(ef + base + 512 * (ch))       = h1;   // spl0: slots 0,1
            *(half8_t*)(ef + base + 512 * (2 + ch))   = h2;   // spl1: slots 2,3
        }
}

// ---- main: 256 rows x ALL 1024 codes per 4-wave block; 64 rows/wave ----
__global__ __launch_bounds__(BLOCK, 1) void vq_main(
    const float* __restrict__ z, const float* __restrict__ cb,
    const _Float16* __restrict__ ef, const float* __restrict__ cn,
    float* __restrict__ zq, float* __restrict__ idx_out) {
    extern __shared__ __align__(16) float zf[];    // 256 x 68 f32 (68 KB dyn)
    __shared__ float sS[ROWS];                     // S*2^9 (exact pow2 scale)
    __shared__ float sCn[K];                       // cn*2^9 (exact pow2 scale)
    __shared__ int   sBi[ROWS];

    const int tid  = threadIdx.x;
    const int lane = tid & 63;
    const int wv   = tid >> 6;            // 0..3, wave rows: wv*64 .. +63
    const int quad = lane >> 4;
    const int l16  = lane & 15;
    const long rowbase = (long)blockIdx.x * ROWS;

    const char* eb = (const char*)ef + 16 * lane;

// B-register loads (4 x 1KB streaming, L2-hot) + scaled cn
#define LOADG(b1_, b2_, cn9_, g_) do {                                        \
        const char* p_ = eb + (size_t)(g_) * 4096;                            \
        b1_[0] = *(const half8_t*)(p_);                                       \
        b1_[1] = *(const half8_t*)(p_ + 1024);                                \
        b2_[0] = *(const half8_t*)(p_ + 2048);                                \
        b2_[1] = *(const half8_t*)(p_ + 3072);                                \
        cn9_ = sCn[(g_) * 16 + l16];                                          \
    } while (0)

    // ---- stage z (coalesced): 256 rows x 64 f32 = 64 KB ----
    const float4* gz = (const float4*)(z + rowbase * D);
#pragma unroll
    for (int i = 0; i < 16; ++i) {
        int idx4 = i * BLOCK + tid;
        int r = idx4 >> 4, j = idx4 & 15;
        *(float4*)(zf + r * 68 + j * 4) = gz[idx4];
    }
#pragma unroll
    for (int i = 0; i < 4; ++i)
        sCn[i * 256 + tid] = __fmul_rn(cn[i * 256 + tid], 512.0f);
    __syncthreads();

    // row norms: 1 thread/row (exact np chain), pre-scaled by 2^9 (exact)
    sS[tid] = __fmul_rn(np_sumsq64_p(zf + tid * 68), 512.0f);

    // A-frags: 4 rt x 2 ch register-resident f16 splits (64 rows/wave)
    half8_t a1[4][2], a2[4][2];
#pragma unroll
    for (int rt = 0; rt < 4; ++rt) {
        const int row = wv * 64 + rt * 16 + l16;
#pragma unroll
        for (int ch = 0; ch < 2; ++ch) {
            const float* p = zf + row * 68 + ch * 32 + quad * 8;
            float4 f0 = *(const float4*)(p);
            float4 f1 = *(const float4*)(p + 4);
            float xs[8] = {f0.x, f0.y, f0.z, f0.w, f1.x, f1.y, f1.z, f1.w};
#pragma unroll
            for (int j = 0; j < 8; ++j) {
                _Float16 h1 = (_Float16)xs[j];
                a1[rt][ch][j] = h1;
                a2[rt][ch][j] =
                    (_Float16)(__fmul_rn(__fsub_rn(xs[j], (float)h1), 2048.0f));
            }
        }
    }
    __syncthreads();   // sS visible to all waves

    float myS9[4][4];
#pragma unroll
    for (int rt = 0; rt < 4; ++rt)
#pragma unroll
        for (int r = 0; r < 4; ++r)
            myS9[rt][r] = sS[wv * 64 + rt * 16 + quad * 4 + r];

    float bv[4][4];
    int   bi[4][4];
#pragma unroll
    for (int rt = 0; rt < 4; ++rt)
#pragma unroll
        for (int r = 0; r < 4; ++r) { bv[rt][r] = INFINITY; bi[rt][r] = 0; }

    const floatx4 Z4g = {0.f, 0.f, 0.f, 0.f};

// Per group: 4 rt x {aM,aC,aD} independent 2-chains (24 MFMAs); EPI
// (R21-exact): ds = fma(fadd(aC,aD), 2^-11, aM); dist9 = (S9-ds)+cn9.
#define COMPUTE(b1_, b2_, cn9_, g_) do {                                      \
        const int kg_ = (g_) * 16 + l16;                                      \
        _Pragma("unroll")                                                     \
        for (int rt = 0; rt < 4; ++rt) {                                      \
            floatx4 aM, aC, aD;                                               \
            aM = __builtin_amdgcn_mfma_f32_16x16x32_f16(a1[rt][0], b1_[0], Z4g, 0, 0, 0); \
            aC = __builtin_amdgcn_mfma_f32_16x16x32_f16(a1[rt][0], b2_[0], Z4g, 0, 0, 0); \
            aD = __builtin_amdgcn_mfma_f32_16x16x32_f16(a2[rt][0], b1_[0], Z4g, 0, 0, 0); \
            aM = __builtin_amdgcn_mfma_f32_16x16x32_f16(a1[rt][1], b1_[1], aM, 0, 0, 0);  \
            aC = __builtin_amdgcn_mfma_f32_16x16x32_f16(a1[rt][1], b2_[1], aC, 0, 0, 0);  \
            aD = __builtin_amdgcn_mfma_f32_16x16x32_f16(a2[rt][1], b1_[1], aD, 0, 0, 0);  \
            _Pragma("unroll")                                                 \
            for (int r = 0; r < 4; ++r) {                                     \
                float sc = __fadd_rn(aC[r], aD[r]);                           \
                float ds = fmaf(sc, 0x1p-11f, aM[r]);                         \
                float d9 = __fadd_rn(__fsub_rn(myS9[rt][r], ds), cn9_);       \
                if (d9 < bv[rt][r]) { bv[rt][r] = d9; bi[rt][r] = kg_; }      \
            }                                                                 \
        }                                                                     \
    } while (0)

    // 2-slot rotation over 64 groups; no barriers, waves free-run
    half8_t b1A[2], b2A[2], b1B[2], b2B[2];
    float cnA, cnB;
    LOADG(b1A, b2A, cnA, 0);
    for (int g = 0; g < 64; g += 2) {
        LOADG(b1B, b2B, cnB, g + 1);
        COMPUTE(b1A, b2A, cnA, g);
        if (g + 2 < 64) LOADG(b1A, b2A, cnA, g + 2);
        COMPUTE(b1B, b2B, cnB, g + 1);
    }

#undef LOADG
#undef COMPUTE

    // reduce over the 16 code-columns; (val, lowest index) = first occurrence
#pragma unroll
    for (int rt = 0; rt < 4; ++rt)
#pragma unroll
        for (int r = 0; r < 4; ++r) {
            float v = bv[rt][r];
            int   x = bi[rt][r];
#pragma unroll
            for (int off = 1; off <= 8; off <<= 1) {
                float ov = __shfl_xor(v, off);
                int   ox = __shfl_xor(x, off);
                if (ov < v || (ov == v && ox < x)) { v = ov; x = ox; }
            }
            if (l16 == 0) {
                const int rl = wv * 64 + rt * 16 + quad * 4 + r;
                sBi[rl] = x;
                idx_out[rowbase + rl] = (float)x;
            }
        }
    __syncthreads();

    // ---- zq gather: zq[row] = cb[bi[row]] (cb L2-hot, coalesced writes) ----
    const float4* cb4 = (const float4*)cb;
    float4* zq4 = (float4*)(zq + rowbase * D);
#pragma unroll
    for (int i = 0; i < 16; ++i) {
        int idx4 = i * BLOCK + tid;
        int r = idx4 >> 4, j = idx4 & 15;
        zq4[idx4] = cb4[(long)sBi[r] * 16 + j];
    }
}

extern "C" void kernel_launch(void* const* d_in, const int* in_sizes, int n_in,
                              void* d_out, int out_size, void* d_ws, size_t ws_size,
                              hipStream_t stream) {
    const float* z  = (const float*)d_in[0];
    const float* cb = (const float*)d_in[1];

    const int n_rows = in_sizes[0] / D;                 // 65536
    float* zq      = (float*)d_out;
    float* idx_out = zq + (long)n_rows * D;

    float*    ws_cn = (float*)((char*)d_ws + WS_CN_OFF);
    _Float16* ws_ef = (_Float16*)((char*)d_ws + WS_EF_OFF);

    vq_pre<<<K / 64, 64, 0, stream>>>(cb, ws_cn, ws_ef);
    vq_main<<<n_rows / ROWS, BLOCK, ROWS * 68 * sizeof(float), stream>>>(
        z, cb, ws_ef, ws_cn, zq, idx_out);
}